// Round 1
// baseline (378.258 us; speedup 1.0000x reference)
//
#include <hip/hip_runtime.h>

#define BATCH 8
#define SDIM 2048
#define KDIM 2048
#define NDIM 2048
#define BM 128
#define BN 128
#define BK 32
#define KTILES (KDIM / BK)

typedef __bf16 bf16_t;
typedef bf16_t bf16x8 __attribute__((ext_vector_type(8)));
typedef float f32x4 __attribute__((ext_vector_type(4)));
typedef unsigned short u16x8 __attribute__((ext_vector_type(8)));

__device__ __forceinline__ unsigned short f2bf(float f) {
    unsigned int u = __builtin_bit_cast(unsigned int, f);
    u += 0x7fffu + ((u >> 16) & 1u);   // round-to-nearest-even
    return (unsigned short)(u >> 16);
}

__global__ __launch_bounds__(256, 2)
void bgemm_kernel(const float* __restrict__ A, const float* __restrict__ B,
                  float* __restrict__ O) {
    // LDS tile layout: [k-octet 0..3][row 0..127][k%8] — 16B-contiguous per
    // (row, octet) so both ds_write_b128 (staging) and ds_read_b128 (MFMA
    // fragments) are stride-16B across lanes: conflict-free.
    __shared__ alignas(16) unsigned short Asl[2][4 * 128 * 8];
    __shared__ alignas(16) unsigned short Bsl[2][4 * 128 * 8];

    const int tid = threadIdx.x;
    const int gid = blockIdx.x;
    // one batch per XCD (gid&7 round-robins XCDs on MI355X)
    const int batch = gid & 7;
    const int t = gid >> 3;            // 0..255 tile id within batch
    const int bm = (t >> 4) * BM;
    const int bn = (t & 15) * BN;

    const float* Ab = A + (size_t)batch * SDIM * KDIM;
    const float* Bb = B + (size_t)batch * KDIM * NDIM;
    float* Ob = O + (size_t)batch * SDIM * NDIM;

    const int lane = tid & 63;
    const int wid = tid >> 6;
    const int wr = wid >> 1;           // wave row 0..1 (64-row half)
    const int wc = wid & 1;            // wave col 0..1 (64-col half)
    const int lr = lane & 15;
    const int lq = lane >> 4;          // k-octet this lane reads

    const int r0 = tid & 127;          // A row / B col staged by this thread
    const int h0 = tid >> 7;           // which 16-wide k-half

    u16x8 areg[2], breg[2];

    f32x4 acc[4][4];
#pragma unroll
    for (int m = 0; m < 4; ++m)
#pragma unroll
        for (int n = 0; n < 4; ++n)
            acc[m][n] = (f32x4){0.f, 0.f, 0.f, 0.f};

    auto stage_regs = [&](int kt) {
        const int k0 = kt * BK;
        // A: row (bm+r0), k in [k0+h0*16, +16): one full 64B line per lane
        const float* ap = Ab + (size_t)(bm + r0) * KDIM + k0 + h0 * 16;
        float4 a0 = *reinterpret_cast<const float4*>(ap + 0);
        float4 a1 = *reinterpret_cast<const float4*>(ap + 4);
        float4 a2 = *reinterpret_cast<const float4*>(ap + 8);
        float4 a3 = *reinterpret_cast<const float4*>(ap + 12);
        u16x8 u;
        u[0] = f2bf(a0.x); u[1] = f2bf(a0.y); u[2] = f2bf(a0.z); u[3] = f2bf(a0.w);
        u[4] = f2bf(a1.x); u[5] = f2bf(a1.y); u[6] = f2bf(a1.z); u[7] = f2bf(a1.w);
        areg[0] = u;
        u[0] = f2bf(a2.x); u[1] = f2bf(a2.y); u[2] = f2bf(a2.z); u[3] = f2bf(a2.w);
        u[4] = f2bf(a3.x); u[5] = f2bf(a3.y); u[6] = f2bf(a3.z); u[7] = f2bf(a3.w);
        areg[1] = u;
        // B: col (bn+r0), k in [k0+h0*16, +16): 16 loads, each coalesced
        // across the 128 consecutive-n threads (transpose happens here)
        const float* bp = Bb + (size_t)(k0 + h0 * 16) * NDIM + bn + r0;
        float f[16];
#pragma unroll
        for (int j = 0; j < 16; ++j) f[j] = bp[(size_t)j * NDIM];
        u16x8 v;
#pragma unroll
        for (int j = 0; j < 8; ++j) v[j] = f2bf(f[j]);
        breg[0] = v;
#pragma unroll
        for (int j = 0; j < 8; ++j) v[j] = f2bf(f[8 + j]);
        breg[1] = v;
    };

    auto regs_to_lds = [&](int b) {
#pragma unroll
        for (int o = 0; o < 2; ++o) {
            *reinterpret_cast<u16x8*>(&Asl[b][((h0 * 2 + o) * 128 + r0) * 8]) = areg[o];
            *reinterpret_cast<u16x8*>(&Bsl[b][((h0 * 2 + o) * 128 + r0) * 8]) = breg[o];
        }
    };

    stage_regs(0);
    regs_to_lds(0);

    int buf = 0;
    for (int kt = 0; kt < KTILES; ++kt) {
        if (kt + 1 < KTILES) stage_regs(kt + 1);  // issue next-tile loads early
        __syncthreads();                          // prev writes to buf complete
        bf16x8 af[4], bfv[4];
#pragma unroll
        for (int m = 0; m < 4; ++m)
            af[m] = *reinterpret_cast<const bf16x8*>(
                &Asl[buf][(lq * 128 + wr * 64 + m * 16 + lr) * 8]);
#pragma unroll
        for (int n = 0; n < 4; ++n)
            bfv[n] = *reinterpret_cast<const bf16x8*>(
                &Bsl[buf][(lq * 128 + wc * 64 + n * 16 + lr) * 8]);
#pragma unroll
        for (int m = 0; m < 4; ++m)
#pragma unroll
            for (int n = 0; n < 4; ++n)
                acc[m][n] = __builtin_amdgcn_mfma_f32_16x16x32_bf16(
                    af[m], bfv[n], acc[m][n], 0, 0, 0);
        if (kt + 1 < KTILES) regs_to_lds(buf ^ 1);  // write next tile, other buffer
        buf ^= 1;
    }

    // epilogue: C/D layout col=lane&15, row=(lane>>4)*4+reg
#pragma unroll
    for (int m = 0; m < 4; ++m) {
        const int row0 = bm + wr * 64 + m * 16 + lq * 4;
#pragma unroll
        for (int n = 0; n < 4; ++n) {
            const int col = bn + wc * 64 + n * 16 + lr;
#pragma unroll
            for (int j = 0; j < 4; ++j)
                Ob[(size_t)(row0 + j) * NDIM + col] = acc[m][n][j];
        }
    }
}

extern "C" void kernel_launch(void* const* d_in, const int* in_sizes, int n_in,
                              void* d_out, int out_size, void* d_ws, size_t ws_size,
                              hipStream_t stream) {
    const float* a = (const float*)d_in[0];
    const float* b = (const float*)d_in[1];
    float* o = (float*)d_out;
    dim3 grid(BATCH * (SDIM / BM) * (NDIM / BN));  // 8*16*16 = 2048
    dim3 block(256);
    hipLaunchKernelGGL(bgemm_kernel, grid, block, 0, stream, a, b, o);
}